// Round 4
// baseline (204.229 us; speedup 1.0000x reference)
//
#include <hip/hip_runtime.h>
#include <math.h>

#define T_TOK 65536
#define K_CODE 1024
#define E_DIM 64
#define DECAYF 0.99f
#define EPSF 1e-5f

// ---- dist_kernel geometry ----
#define TT 256            // tokens per block (8 token-groups x 32 rows)
#define QCAP 2048         // candidate queue capacity (expected ~640)
// acc-domain margin. dist = xn - 2*acc + wn, so dist-window = 2*HACC.
// Rigorous need: (2*bf16_err + wn_max)/1 -> acc-margin >= (9.8e-4 + 6.1e-5)/2
// ~= 5.2e-4. HACC = 1.3e-3 gives ~2.5x slack (same effective window as the
// harness-verified rounds 2/3 MARGIN=2.5e-3).
#define HACC 1.3e-3f

typedef short short8 __attribute__((ext_vector_type(8)));
typedef float f32x16 __attribute__((ext_vector_type(16)));

// --- exact-rounding helpers: block ffp-contract=fast fusion ---
__device__ __forceinline__ float mul_nf(float a, float b) {
#pragma clang fp contract(off)
    return a * b;
}
__device__ __forceinline__ float add_nf(float a, float b) {
#pragma clang fp contract(off)
    return a + b;
}
__device__ __forceinline__ float sub_nf(float a, float b) {
#pragma clang fp contract(off)
    return a - b;
}

// numpy pairwise ||x||^2 from a global row pointer (float4 loads)
__device__ __forceinline__ float np_sq_row(const float* xrow) {
    const float4* xp = reinterpret_cast<const float4*>(xrow);
    float r[8];
#pragma unroll
    for (int g = 0; g < 8; ++g) {
        float4 va = xp[2 * g], vb = xp[2 * g + 1];
        float e[8] = {va.x, va.y, va.z, va.w, vb.x, vb.y, vb.z, vb.w};
#pragma unroll
        for (int j = 0; j < 8; ++j) {
            if (g == 0) r[j] = mul_nf(e[j], e[j]);
            else        r[j] = add_nf(r[j], mul_nf(e[j], e[j]));
        }
    }
    float s01 = add_nf(r[0], r[1]);
    float s23 = add_nf(r[2], r[3]);
    float s45 = add_nf(r[4], r[5]);
    float s67 = add_nf(r[6], r[7]);
    return add_nf(add_nf(s01, s23), add_nf(s45, s67));
}

__device__ __forceinline__ unsigned f2bf_rne(float f) {
    unsigned u = __float_as_uint(f);
    u += 0x7FFFu + ((u >> 16) & 1u);
    return (u >> 16);
}

// exact fp32 recheck: bit-identical arithmetic to the verified argmin chain
// (ascending i single-accumulator FMA, dist = fl(fl(xn - fl(d+d)) + wn)),
// first-min semantics via u64 (monotone_dist<<32 | code) atomicMin on LDS.
__device__ __forceinline__ void exact_key(int t0, int tl, int code,
                                          const float* __restrict__ z_e,
                                          const float* __restrict__ embed,
                                          const float* xn_s, const float* wn_s,
                                          unsigned long long* key_s) {
    const float4* xp = reinterpret_cast<const float4*>(z_e + (size_t)(t0 + tl) * E_DIM);
    const float4* wp = reinterpret_cast<const float4*>(embed + (size_t)code * E_DIM);
    float d = 0.f;
#pragma unroll
    for (int m = 0; m < 16; ++m) {
        float4 x4 = xp[m];
        float4 w4 = wp[m];
        d = __builtin_fmaf(x4.x, w4.x, d);
        d = __builtin_fmaf(x4.y, w4.y, d);
        d = __builtin_fmaf(x4.z, w4.z, d);
        d = __builtin_fmaf(x4.w, w4.w, d);
    }
    float dist = add_nf(sub_nf(xn_s[tl], d + d), wn_s[code]);
    unsigned b = __float_as_uint(dist);
    unsigned mk = (b & 0x80000000u) ? ~b : (b | 0x80000000u);
    atomicMin(key_s + tl, ((unsigned long long)mk << 32) | (unsigned)code);
}

// ws layout (floats):
// [0]                  diff accumulator
// [1]                  n (sum of new_cluster_size)
// [2, 16)              pad
// [16, 16+8192)        onehot replicas (8*1024)
// [8208, +nrep*65536)  embed_sum replicas
// single contiguous memset: [0, 8208 + nrep*65536)

// MFMA approx-filter + exact-recheck argmin, fully fused.
// Block = 1024 thr = 16 waves (4 waves/SIMD for latency hiding); 256 tokens;
// 256 blocks = 1 block/CU. Wave w: token-group tg=w&7 (rows 32*tg..+31),
// code-half ch=w>>3 (codes ch*512..+511, 16 tiles of 32).
// Prologue (per block): thread tid converts embed row tid to bf16 into the
// swizzled 128 KB LDS codebook AND computes wnorm (np-exact) -> no separate
// wnorm kernel, no global w16 round-trip.
// Filter tracks RAW MFMA acc maxima (argmin dist == argmax acc up to wn,
// folded into HACC) -> pass-1 body is 16 v_max only.
// Pass 2 re-runs tiles, enqueues (tok,code) with acc >= gmax - HACC; drain
// does the exact fp32 chain -> key_s; fused epilogue (z_q/diff/EMA scatter).
__global__ __launch_bounds__(1024, 4) void dist_kernel(const float* __restrict__ z_e,
                                                       const float* __restrict__ embed,
                                                       float* __restrict__ out_zq,
                                                       float* __restrict__ out_ind,
                                                       float* __restrict__ diff_acc,
                                                       float* __restrict__ esum_rep,
                                                       float* __restrict__ onehot_rep,
                                                       int rep_mask) {
    __shared__ unsigned short Ws[K_CODE * E_DIM];  // 128 KB, swizzled slots
    __shared__ float wn_s[K_CODE];                 // 4 KB
    __shared__ float xn_s[TT];                     // 1 KB
    __shared__ float m_s[2][TT];                   // 2 KB per-half acc max
    __shared__ unsigned long long key_s[TT];       // 2 KB
    __shared__ unsigned q_s[QCAP];                 // 8 KB
    __shared__ int qc_s;

    int tid = threadIdx.x;
    int lane = tid & 63;
    int wave = tid >> 6;
    int g = lane >> 5;        // k-group within MFMA operand
    int tg = wave & 7;        // token group (32 rows)
    int ch = wave >> 3;       // code half
    int t0 = blockIdx.x * TT;

    if (tid == 0) qc_s = 0;
    if (tid < TT) {
        key_s[tid] = ~0ull;
        // ||x||^2 per token (exact numpy pairwise)
        xn_s[tid] = np_sq_row(z_e + (size_t)(t0 + tid) * E_DIM);
    }

    // --- fused codebook convert + stage + wnorm: thread owns embed row tid ---
    {
        int row = tid;
        const float4* wp = reinterpret_cast<const float4*>(embed + (size_t)row * E_DIM);
        uint4* WsQ = reinterpret_cast<uint4*>(Ws);
        float r8[8];
#pragma unroll
        for (int gq = 0; gq < 8; ++gq) {
            float4 va = wp[2 * gq], vb = wp[2 * gq + 1];
            float e[8] = {va.x, va.y, va.z, va.w, vb.x, vb.y, vb.z, vb.w};
#pragma unroll
            for (int j = 0; j < 8; ++j) {
                if (gq == 0) r8[j] = mul_nf(e[j], e[j]);
                else         r8[j] = add_nf(r8[j], mul_nf(e[j], e[j]));
            }
            unsigned p0 = f2bf_rne(e[0]) | (f2bf_rne(e[1]) << 16);
            unsigned p1 = f2bf_rne(e[2]) | (f2bf_rne(e[3]) << 16);
            unsigned p2 = f2bf_rne(e[4]) | (f2bf_rne(e[5]) << 16);
            unsigned p3 = f2bf_rne(e[6]) | (f2bf_rne(e[7]) << 16);
            // logical slot gq (elems 8gq..8gq+7) at phys slot gq ^ (row&7)
            WsQ[row * 8 + (gq ^ (row & 7))] = make_uint4(p0, p1, p2, p3);
        }
        float s01 = add_nf(r8[0], r8[1]);
        float s23 = add_nf(r8[2], r8[3]);
        float s45 = add_nf(r8[4], r8[5]);
        float s67 = add_nf(r8[6], r8[7]);
        wn_s[row] = add_nf(add_nf(s01, s23), add_nf(s45, s67));  // np-exact
    }

    // a-frags: lane supplies A[m = lane&31][k = 16*kc + 8*g + j], bf16.
    // (wave pairs w and w+8 load the same rows; L1/L2 absorbs it)
    int arow = tg * 32 + (lane & 31);
    const float* xrow = z_e + (size_t)(t0 + arow) * E_DIM;
    short8 afr[4];
#pragma unroll
    for (int kc = 0; kc < 4; ++kc) {
        int base = kc * 16 + g * 8;
        float4 a = *reinterpret_cast<const float4*>(xrow + base);
        float4 b = *reinterpret_cast<const float4*>(xrow + base + 4);
        afr[kc][0] = (short)f2bf_rne(a.x);
        afr[kc][1] = (short)f2bf_rne(a.y);
        afr[kc][2] = (short)f2bf_rne(a.z);
        afr[kc][3] = (short)f2bf_rne(a.w);
        afr[kc][4] = (short)f2bf_rne(b.x);
        afr[kc][5] = (short)f2bf_rne(b.y);
        afr[kc][6] = (short)f2bf_rne(b.z);
        afr[kc][7] = (short)f2bf_rne(b.w);
    }

    __syncthreads();  // Ws, wn_s, xn_s, key_s ready

    // ---- pass 1: per-(lane,row) raw-acc max over this wave's 16 tiles ----
    float maxr[16];
#pragma unroll
    for (int r = 0; r < 16; ++r) maxr[r] = -INFINITY;

#pragma unroll 2
    for (int tt = 0; tt < 16; ++tt) {
        int code = (ch * 16 + tt) * 32 + (lane & 31);
        f32x16 acc;
#pragma unroll
        for (int i = 0; i < 16; ++i) acc[i] = 0.f;
#pragma unroll
        for (int kc = 0; kc < 4; ++kc) {
            int ps = (2 * kc + g) ^ (code & 7);
            short8 bfr = *reinterpret_cast<const short8*>(&Ws[code * E_DIM + ps * 8]);
            acc = __builtin_amdgcn_mfma_f32_32x32x16_bf16(afr[kc], bfr, acc, 0, 0, 0);
        }
#pragma unroll
        for (int r = 0; r < 16; ++r) maxr[r] = fmaxf(maxr[r], acc[r]);
    }

    // cross-column reduce (xor masks < 32 stay inside the lane>>5 group)
#pragma unroll
    for (int off = 1; off < 32; off <<= 1) {
#pragma unroll
        for (int r = 0; r < 16; ++r)
            maxr[r] = fmaxf(maxr[r], __shfl_xor(maxr[r], off, 64));
    }
    // publish this half's per-token max
    if ((lane & 31) == 0) {
#pragma unroll
        for (int r = 0; r < 16; ++r) {
            int row = (r & 3) + 8 * (r >> 2) + 4 * g;
            m_s[ch][tg * 32 + row] = maxr[r];
        }
    }
    __syncthreads();

    // per-lane enqueue thresholds: global max across halves, minus margin
    float thr[16];
#pragma unroll
    for (int r = 0; r < 16; ++r) {
        int row = (r & 3) + 8 * (r >> 2) + 4 * g;
        int tok = tg * 32 + row;
        thr[r] = fmaxf(m_s[0][tok], m_s[1][tok]) - HACC;  // broadcast reads
    }

    // ---- pass 2: enqueue margin candidates ----
#pragma unroll 2
    for (int tt = 0; tt < 16; ++tt) {
        int code = (ch * 16 + tt) * 32 + (lane & 31);
        f32x16 acc;
#pragma unroll
        for (int i = 0; i < 16; ++i) acc[i] = 0.f;
#pragma unroll
        for (int kc = 0; kc < 4; ++kc) {
            int ps = (2 * kc + g) ^ (code & 7);
            short8 bfr = *reinterpret_cast<const short8*>(&Ws[code * E_DIM + ps * 8]);
            acc = __builtin_amdgcn_mfma_f32_32x32x16_bf16(afr[kc], bfr, acc, 0, 0, 0);
        }
        float tmax = -INFINITY;
#pragma unroll
        for (int r = 0; r < 16; ++r) tmax = fmaxf(tmax, acc[r] - thr[r]);
        if (tmax >= 0.f) {
#pragma unroll
            for (int r = 0; r < 16; ++r) {
                if (acc[r] >= thr[r]) {
                    int row = (r & 3) + 8 * (r >> 2) + 4 * g;
                    int tl = tg * 32 + row;
                    int slot = atomicAdd(&qc_s, 1);
                    if (slot < QCAP)
                        q_s[slot] = ((unsigned)tl << 10) | (unsigned)code;
                    else  // overflow fallback: exact inline (never in practice)
                        exact_key(t0, tl, code, z_e, embed, xn_s, wn_s, key_s);
                }
            }
        }
    }
    __syncthreads();

    // drain candidate queue with the exact fp32 chain (lane-parallel)
    int qn = qc_s;
    if (qn > QCAP) qn = QCAP;
    for (int e = tid; e < qn; e += 1024) {
        unsigned q = q_s[e];
        int tl = (int)(q >> 10);
        int code = (int)(q & 1023u);
        exact_key(t0, tl, code, z_e, embed, xn_s, wn_s, key_s);
    }
    __syncthreads();

    // ---- fused epilogue: ind, z_q, diff, EMA scatter (16 tokens/wave) ----
    if (tid < TT) out_ind[t0 + tid] = (float)(unsigned)(key_s[tid] & 1023ull);

    int rep = blockIdx.x & rep_mask;
    float* esum = esum_rep + (size_t)rep * (K_CODE * E_DIM);
    float* onehot = onehot_rep + (size_t)rep * K_CODE;

    float ds = 0.f;
#pragma unroll 4
    for (int it = 0; it < 16; ++it) {
        int tl = wave * 16 + it;                        // wave-uniform
        int bi = (int)(unsigned)(key_s[tl] & 1023ull);  // broadcast
        float xv = z_e[(size_t)(t0 + tl) * E_DIM + lane];   // coalesced row
        float wv = embed[(size_t)bi * E_DIM + lane];        // coalesced row
        float rr = sub_nf(wv, xv);                          // np: r = fl(w-x)
        out_zq[(size_t)(t0 + tl) * E_DIM + lane] = add_nf(xv, rr);  // fl(x+r)
        ds = __builtin_fmaf(rr, rr, ds);
        atomicAdd(&esum[(size_t)bi * E_DIM + lane], xv);
        if (lane == 0) atomicAdd(&onehot[bi], 1.0f);
    }
#pragma unroll
    for (int o = 32; o > 0; o >>= 1) ds += __shfl_down(ds, o, 64);
    if (lane == 0) atomicAdd(diff_acc, ds);
}

// ncs, n, diff: single block (tiny)
__global__ __launch_bounds__(1024) void finalize_cs_kernel(const float* __restrict__ cluster_size,
                                                           const float* __restrict__ onehot_rep,
                                                           const float* __restrict__ ws_diff,
                                                           float* __restrict__ out_diff,
                                                           float* __restrict__ out_ncs,
                                                           float* __restrict__ ws_n,
                                                           int nrep) {
    int k = threadIdx.x;
    float oh = 0.f;
    for (int r = 0; r < nrep; ++r) oh += onehot_rep[(size_t)r * K_CODE + k];
    float ncs = DECAYF * cluster_size[k] + (1.0f - DECAYF) * oh;
    out_ncs[k] = ncs;

    __shared__ float red[1024];
    red[k] = ncs;
    __syncthreads();
#pragma unroll
    for (int s = 512; s > 0; s >>= 1) {
        if (k < s) red[k] += red[k + s];
        __syncthreads();
    }
    if (k == 0) {
        ws_n[0] = red[0];
        out_diff[0] = ws_diff[0] * (1.0f / 4194304.0f);  // /2^22 exact
    }
}

// embed_avg / embed update spread across 64 blocks
__global__ __launch_bounds__(256) void finalize_embed_kernel(const float* __restrict__ embed_avg,
                                                             const float* __restrict__ esum_rep,
                                                             const float* __restrict__ out_ncs,
                                                             const float* __restrict__ ws_n,
                                                             float* __restrict__ out_ne,
                                                             float* __restrict__ out_nea,
                                                             int nrep) {
    int gid = blockIdx.x * 256 + threadIdx.x;
    int k = gid >> 4;        // row
    int c = gid & 15;        // float4 chunk
    float n = ws_n[0];
    float ncs = out_ncs[k];
    float cs = (ncs + EPSF) / (n + (float)K_CODE * EPSF) * n;

    size_t off = (size_t)k * E_DIM + (size_t)c * 4;
    float4 s4 = make_float4(0.f, 0.f, 0.f, 0.f);
    for (int r = 0; r < nrep; ++r) {
        float4 v = *reinterpret_cast<const float4*>(esum_rep + (size_t)r * (K_CODE * E_DIM) + off);
        s4.x += v.x; s4.y += v.y; s4.z += v.z; s4.w += v.w;
    }
    float4 a = *reinterpret_cast<const float4*>(embed_avg + off);
    float4 nea, ne;
    nea.x = DECAYF * a.x + (1.0f - DECAYF) * s4.x;
    nea.y = DECAYF * a.y + (1.0f - DECAYF) * s4.y;
    nea.z = DECAYF * a.z + (1.0f - DECAYF) * s4.z;
    nea.w = DECAYF * a.w + (1.0f - DECAYF) * s4.w;
    ne.x = nea.x / cs; ne.y = nea.y / cs; ne.z = nea.z / cs; ne.w = nea.w / cs;
    *reinterpret_cast<float4*>(out_nea + off) = nea;
    *reinterpret_cast<float4*>(out_ne + off) = ne;
}

extern "C" void kernel_launch(void* const* d_in, const int* in_sizes, int n_in,
                              void* d_out, int out_size, void* d_ws, size_t ws_size,
                              hipStream_t stream) {
    const float* z_e = (const float*)d_in[0];
    const float* embed = (const float*)d_in[1];
    const float* cluster_size = (const float*)d_in[2];
    const float* embed_avg = (const float*)d_in[3];

    float* out = (float*)d_out;
    float* o_zq = out;                   // 4194304
    float* o_diff = out + 4194304;       // 1
    float* o_ind = out + 4194305;        // 65536
    float* o_ne = out + 4194305 + 65536; // 65536
    float* o_ncs = o_ne + 65536;         // 1024
    float* o_nea = o_ncs + 1024;         // 65536

    float* ws = (float*)d_ws;
    float* ws_diff = ws + 0;
    float* ws_n = ws + 1;
    float* ws_onehot = ws + 16;          // 8*1024
    float* ws_esum = ws + 8208;          // nrep*65536

    int nrep = 1;
    while (nrep < 8 &&
           (size_t)(8208 + (size_t)(2 * nrep) * 65536) * sizeof(float) <= ws_size)
        nrep *= 2;

    // one contiguous clear: diff, n, pad, onehot, esum
    hipMemsetAsync(ws, 0, (size_t)(8208 + (size_t)nrep * 65536) * sizeof(float), stream);

    dist_kernel<<<T_TOK / TT, 1024, 0, stream>>>(z_e, embed, o_zq, o_ind, ws_diff,
                                                 ws_esum, ws_onehot, nrep - 1);
    finalize_cs_kernel<<<1, 1024, 0, stream>>>(cluster_size, ws_onehot, ws_diff,
                                               o_diff, o_ncs, ws_n, nrep);
    finalize_embed_kernel<<<64, 256, 0, stream>>>(embed_avg, ws_esum, o_ncs, ws_n,
                                                  o_ne, o_nea, nrep);
}

// Round 5
// 193.719 us; speedup vs baseline: 1.0543x; 1.0543x over previous
//
#include <hip/hip_runtime.h>
#include <math.h>

#define T_TOK 65536
#define K_CODE 1024
#define E_DIM 64
#define DECAYF 0.99f
#define EPSF 1e-5f

// ---- dist_kernel geometry ----
#define TT 256            // tokens per block (8 waves x 32 rows)
#define HCODE 512         // codes per block (half the codebook)
#define QCAP 2048         // candidate queue capacity (expected ~640)
// acc-domain margin (r4-harness-verified filter): dist = xn - 2*acc + wn, so
// dist-window = 2*HACC. Rigorous need: acc-margin >= (2*bf16_err + wn_max)/2
// ~= 5.2e-4. HACC = 1.3e-3 gives ~2.5x slack. Half-local max is a correct
// superset filter: each half's true best is within HACC of that half's max.
#define HACC 1.3e-3f

typedef short short8 __attribute__((ext_vector_type(8)));
typedef float f32x16 __attribute__((ext_vector_type(16)));

// --- exact-rounding helpers: block ffp-contract=fast fusion ---
__device__ __forceinline__ float mul_nf(float a, float b) {
#pragma clang fp contract(off)
    return a * b;
}
__device__ __forceinline__ float add_nf(float a, float b) {
#pragma clang fp contract(off)
    return a + b;
}
__device__ __forceinline__ float sub_nf(float a, float b) {
#pragma clang fp contract(off)
    return a - b;
}

// numpy pairwise ||x||^2 from a global row pointer (float4 loads)
__device__ __forceinline__ float np_sq_row(const float* xrow) {
    const float4* xp = reinterpret_cast<const float4*>(xrow);
    float r[8];
#pragma unroll
    for (int g = 0; g < 8; ++g) {
        float4 va = xp[2 * g], vb = xp[2 * g + 1];
        float e[8] = {va.x, va.y, va.z, va.w, vb.x, vb.y, vb.z, vb.w};
#pragma unroll
        for (int j = 0; j < 8; ++j) {
            if (g == 0) r[j] = mul_nf(e[j], e[j]);
            else        r[j] = add_nf(r[j], mul_nf(e[j], e[j]));
        }
    }
    float s01 = add_nf(r[0], r[1]);
    float s23 = add_nf(r[2], r[3]);
    float s45 = add_nf(r[4], r[5]);
    float s67 = add_nf(r[6], r[7]);
    return add_nf(add_nf(s01, s23), add_nf(s45, s67));
}

__device__ __forceinline__ unsigned f2bf_rne(float f) {
    unsigned u = __float_as_uint(f);
    u += 0x7FFFu + ((u >> 16) & 1u);
    return (u >> 16);
}

// exact fp32 recheck: bit-identical arithmetic to the verified argmin chain
// (ascending i single-accumulator FMA, dist = fl(fl(xn - fl(d+d)) + wn)),
// first-min semantics via u64 (monotone_dist<<32 | code) atomicMin on LDS.
__device__ __forceinline__ void exact_key(int t0, int tl, int code, float wn,
                                          const float* __restrict__ z_e,
                                          const float* __restrict__ embed,
                                          const float* xn_s,
                                          unsigned long long* key_s) {
    const float4* xp = reinterpret_cast<const float4*>(z_e + (size_t)(t0 + tl) * E_DIM);
    const float4* wp = reinterpret_cast<const float4*>(embed + (size_t)code * E_DIM);
    float d = 0.f;
#pragma unroll
    for (int m = 0; m < 16; ++m) {
        float4 x4 = xp[m];
        float4 w4 = wp[m];
        d = __builtin_fmaf(x4.x, w4.x, d);
        d = __builtin_fmaf(x4.y, w4.y, d);
        d = __builtin_fmaf(x4.z, w4.z, d);
        d = __builtin_fmaf(x4.w, w4.w, d);
    }
    float dist = add_nf(sub_nf(xn_s[tl], d + d), wn);
    unsigned b = __float_as_uint(dist);
    unsigned mk = (b & 0x80000000u) ? ~b : (b | 0x80000000u);
    atomicMin(key_s + tl, ((unsigned long long)mk << 32) | (unsigned)code);
}

// ws layout (floats):
// [0]                          diff accumulator
// [1, 16)                      pad
// [16, 16+8192)                onehot replicas (8*1024)
// [8208, +nrep*65536)          embed_sum replicas
// [8208+nrep*65536, +262144)   keys2: u64[65536][2] per-half winner keys
//                              (fully written by dist_kernel -> NOT memset)
// single contiguous memset: [0, 8208 + nrep*65536)

// MFMA approx-filter + exact-recheck argmin over HALF the codebook.
// Block = 512 thr = 8 waves; 256 tokens; half h = blockIdx&1 owns codes
// [h*512, h*512+512). LDS = 64 KB half-codebook + ~13 KB misc -> TWO blocks
// co-resident per CU (4 waves/SIMD; independent blocks fill each other's
// prologue/drain latency phases — the r2-vs-r3 lesson). No launch_bounds
// occupancy arg: round 4 showed capping VGPR below live state (64 < ~96)
// causes spill traffic that eats the occupancy gain.
// Wave w owns token rows 32w..32w+31 and scans all 16 tiles of the half.
// Pass 1 tracks raw MFMA acc maxima (r4-verified filter); pass 2 enqueues
// candidates within HACC of the half max; drain runs the exact fp32 chain
// into LDS key_s; per-half keys plain-stored to keys2 (no global atomics).
__global__ __launch_bounds__(512) void dist_kernel(const float* __restrict__ z_e,
                                                   const float* __restrict__ embed,
                                                   unsigned long long* __restrict__ keys2) {
    __shared__ unsigned short Ws[HCODE * E_DIM];   // 64 KB, swizzled slots
    __shared__ float wn_s[HCODE];                  // 2 KB
    __shared__ float xn_s[TT];                     // 1 KB
    __shared__ unsigned long long key_s[TT];       // 2 KB
    __shared__ unsigned q_s[QCAP];                 // 8 KB
    __shared__ int qc_s;

    int tid = threadIdx.x;
    int lane = tid & 63;
    int wave = tid >> 6;
    int g = lane >> 5;              // k-group within MFMA operand
    int h = blockIdx.x & 1;         // code half
    int t0 = (blockIdx.x >> 1) * TT;
    int kbase = h * HCODE;

    if (tid == 0) qc_s = 0;
    if (tid < TT) {
        key_s[tid] = ~0ull;
        // ||x||^2 per token (exact numpy pairwise)
        xn_s[tid] = np_sq_row(z_e + (size_t)(t0 + tid) * E_DIM);
    }

    // --- fused half-codebook convert + stage + wnorm: thread owns row tid ---
    {
        int row = tid;  // 0..511 local row
        const float4* wp =
            reinterpret_cast<const float4*>(embed + (size_t)(kbase + row) * E_DIM);
        uint4* WsQ = reinterpret_cast<uint4*>(Ws);
        float r8[8];
#pragma unroll
        for (int gq = 0; gq < 8; ++gq) {
            float4 va = wp[2 * gq], vb = wp[2 * gq + 1];
            float e[8] = {va.x, va.y, va.z, va.w, vb.x, vb.y, vb.z, vb.w};
#pragma unroll
            for (int j = 0; j < 8; ++j) {
                if (gq == 0) r8[j] = mul_nf(e[j], e[j]);
                else         r8[j] = add_nf(r8[j], mul_nf(e[j], e[j]));
            }
            unsigned p0 = f2bf_rne(e[0]) | (f2bf_rne(e[1]) << 16);
            unsigned p1 = f2bf_rne(e[2]) | (f2bf_rne(e[3]) << 16);
            unsigned p2 = f2bf_rne(e[4]) | (f2bf_rne(e[5]) << 16);
            unsigned p3 = f2bf_rne(e[6]) | (f2bf_rne(e[7]) << 16);
            // logical slot gq (elems 8gq..8gq+7) at phys slot gq ^ (row&7)
            WsQ[row * 8 + (gq ^ (row & 7))] = make_uint4(p0, p1, p2, p3);
        }
        float s01 = add_nf(r8[0], r8[1]);
        float s23 = add_nf(r8[2], r8[3]);
        float s45 = add_nf(r8[4], r8[5]);
        float s67 = add_nf(r8[6], r8[7]);
        wn_s[row] = add_nf(add_nf(s01, s23), add_nf(s45, s67));  // np-exact
    }

    // a-frags: lane supplies A[m = lane&31][k = 16*kc + 8*g + j], bf16.
    int arow = wave * 32 + (lane & 31);
    const float* xrow = z_e + (size_t)(t0 + arow) * E_DIM;
    short8 afr[4];
#pragma unroll
    for (int kc = 0; kc < 4; ++kc) {
        int base = kc * 16 + g * 8;
        float4 a = *reinterpret_cast<const float4*>(xrow + base);
        float4 b = *reinterpret_cast<const float4*>(xrow + base + 4);
        afr[kc][0] = (short)f2bf_rne(a.x);
        afr[kc][1] = (short)f2bf_rne(a.y);
        afr[kc][2] = (short)f2bf_rne(a.z);
        afr[kc][3] = (short)f2bf_rne(a.w);
        afr[kc][4] = (short)f2bf_rne(b.x);
        afr[kc][5] = (short)f2bf_rne(b.y);
        afr[kc][6] = (short)f2bf_rne(b.z);
        afr[kc][7] = (short)f2bf_rne(b.w);
    }

    __syncthreads();  // Ws, wn_s, xn_s, key_s ready

    // ---- pass 1: per-(lane,row) raw-acc max over the half's 16 tiles ----
    float maxr[16];
#pragma unroll
    for (int r = 0; r < 16; ++r) maxr[r] = -INFINITY;

#pragma unroll 2
    for (int tile = 0; tile < 16; ++tile) {
        int cloc = tile * 32 + (lane & 31);
        f32x16 acc;
#pragma unroll
        for (int i = 0; i < 16; ++i) acc[i] = 0.f;
#pragma unroll
        for (int kc = 0; kc < 4; ++kc) {
            int ps = (2 * kc + g) ^ (cloc & 7);
            short8 bfr = *reinterpret_cast<const short8*>(&Ws[cloc * E_DIM + ps * 8]);
            acc = __builtin_amdgcn_mfma_f32_32x32x16_bf16(afr[kc], bfr, acc, 0, 0, 0);
        }
#pragma unroll
        for (int r = 0; r < 16; ++r) maxr[r] = fmaxf(maxr[r], acc[r]);
    }

    // cross-column reduce (xor masks < 32 stay inside the lane>>5 group),
    // then fold the margin in-place: maxr becomes the enqueue threshold.
#pragma unroll
    for (int off = 1; off < 32; off <<= 1) {
#pragma unroll
        for (int r = 0; r < 16; ++r)
            maxr[r] = fmaxf(maxr[r], __shfl_xor(maxr[r], off, 64));
    }
#pragma unroll
    for (int r = 0; r < 16; ++r) maxr[r] -= HACC;

    // ---- pass 2: enqueue margin candidates ----
#pragma unroll 2
    for (int tile = 0; tile < 16; ++tile) {
        int cloc = tile * 32 + (lane & 31);
        f32x16 acc;
#pragma unroll
        for (int i = 0; i < 16; ++i) acc[i] = 0.f;
#pragma unroll
        for (int kc = 0; kc < 4; ++kc) {
            int ps = (2 * kc + g) ^ (cloc & 7);
            short8 bfr = *reinterpret_cast<const short8*>(&Ws[cloc * E_DIM + ps * 8]);
            acc = __builtin_amdgcn_mfma_f32_32x32x16_bf16(afr[kc], bfr, acc, 0, 0, 0);
        }
        float tmax = -INFINITY;
#pragma unroll
        for (int r = 0; r < 16; ++r) tmax = fmaxf(tmax, acc[r] - maxr[r]);
        if (tmax >= 0.f) {  // rare
#pragma unroll
            for (int r = 0; r < 16; ++r) {
                if (acc[r] >= maxr[r]) {
                    int row = (r & 3) + 8 * (r >> 2) + 4 * g;
                    int tl = wave * 32 + row;
                    int slot = atomicAdd(&qc_s, 1);
                    if (slot < QCAP)
                        q_s[slot] = ((unsigned)tl << 9) | (unsigned)cloc;
                    else  // overflow fallback: exact inline (never in practice)
                        exact_key(t0, tl, kbase + cloc, wn_s[cloc], z_e, embed,
                                  xn_s, key_s);
                }
            }
        }
    }
    __syncthreads();

    // drain candidate queue with the exact fp32 chain
    int qn = qc_s;
    if (qn > QCAP) qn = QCAP;
    for (int e = tid; e < qn; e += 512) {
        unsigned q = q_s[e];
        int tl = (int)(q >> 9);
        int cloc = (int)(q & 511u);
        exact_key(t0, tl, kbase + cloc, wn_s[cloc], z_e, embed, xn_s, key_s);
    }
    __syncthreads();

    // per-half winner: plain coalesced store, no global atomics, no memset
    if (tid < TT) keys2[(size_t)(t0 + tid) * 2 + h] = key_s[tid];
}

// Combine: gather winner, straight-through z_q + diff partial, fused EMA
// scatter (round-1-harness-verified body; only the key read changed to the
// min of the two per-half keys — u64 lexicographic min == np first-min,
// code index lives in the low bits so ties resolve to the smaller code).
__global__ __launch_bounds__(256) void combine_kernel(const float* __restrict__ z_e,
                                                      const float* __restrict__ embed,
                                                      const unsigned long long* __restrict__ keys2,
                                                      float* __restrict__ out_zq,
                                                      float* __restrict__ out_ind,
                                                      float* __restrict__ diff_acc,
                                                      float* __restrict__ esum_rep,
                                                      float* __restrict__ onehot_rep,
                                                      int rep_mask) {
    __shared__ int sidx[64];
    __shared__ float sred[4];
    int tid = threadIdx.x;
    int t0 = blockIdx.x * 64;

    if (tid < 64) {
        unsigned long long k0 = keys2[(size_t)(t0 + tid) * 2];
        unsigned long long k1 = keys2[(size_t)(t0 + tid) * 2 + 1];
        unsigned long long kv = k0 < k1 ? k0 : k1;
        int bi = (int)(kv & 0x3FFull);
        sidx[tid] = bi;
        out_ind[t0 + tid] = (float)bi;
    }
    __syncthreads();

    float ds = 0.f;
#pragma unroll
    for (int u = 0; u < 4; ++u) {
        int v = u * 256 + tid;
        int tl = v >> 4;
        int c = v & 15;
        int bi = sidx[tl];
        float4 w4 = *reinterpret_cast<const float4*>(embed + (size_t)bi * E_DIM + c * 4);
        float4 x4 = *reinterpret_cast<const float4*>(z_e + (size_t)(t0 + tl) * E_DIM + c * 4);
        float rx = sub_nf(w4.x, x4.x);
        float ry = sub_nf(w4.y, x4.y);
        float rz = sub_nf(w4.z, x4.z);
        float rw = sub_nf(w4.w, x4.w);
        float4 o;
        o.x = add_nf(x4.x, rx);
        o.y = add_nf(x4.y, ry);
        o.z = add_nf(x4.z, rz);
        o.w = add_nf(x4.w, rw);
        *reinterpret_cast<float4*>(out_zq + (size_t)(t0 + tl) * E_DIM + c * 4) = o;
        ds = __builtin_fmaf(rx, rx, ds);
        ds = __builtin_fmaf(ry, ry, ds);
        ds = __builtin_fmaf(rz, rz, ds);
        ds = __builtin_fmaf(rw, rw, ds);
    }
#pragma unroll
    for (int o = 32; o > 0; o >>= 1) ds += __shfl_down(ds, o, 64);
    if ((tid & 63) == 0) sred[tid >> 6] = ds;
    __syncthreads();
    if (tid == 0) atomicAdd(diff_acc, sred[0] + sred[1] + sred[2] + sred[3]);

    // fused EMA scatter, lane = dim -> one coalesced 256B row-atomic per token
    int lane = tid & 63;
    int wv = tid >> 6;
    int rep = blockIdx.x & rep_mask;
    float* esum = esum_rep + (size_t)rep * (K_CODE * E_DIM);
    float* onehot = onehot_rep + (size_t)rep * K_CODE;
#pragma unroll
    for (int j = 0; j < 16; ++j) {
        int tl = wv * 16 + j;
        int bi = sidx[tl];
        float xv = z_e[(size_t)(t0 + tl) * E_DIM + lane];
        atomicAdd(&esum[(size_t)bi * E_DIM + lane], xv);
        if (lane == 0) atomicAdd(&onehot[bi], 1.0f);
    }
}

// Fused finalize: every block redundantly computes ncs[1024] + n (36 KB of
// reads — cheap) with the SAME reduction tree as the previously-verified
// finalize_cs (levels s=512..1, red[idx]+=red[idx+s]); block 0 writes
// out_ncs/out_diff; each block then updates its 16 embed rows (identical
// row/chunk mapping and arithmetic to the verified finalize_embed).
__global__ __launch_bounds__(256) void finalize_kernel(const float* __restrict__ cluster_size,
                                                       const float* __restrict__ onehot_rep,
                                                       const float* __restrict__ ws_diff,
                                                       const float* __restrict__ embed_avg,
                                                       const float* __restrict__ esum_rep,
                                                       float* __restrict__ out_diff,
                                                       float* __restrict__ out_ncs,
                                                       float* __restrict__ out_ne,
                                                       float* __restrict__ out_nea,
                                                       int nrep) {
    __shared__ float ncs_s[K_CODE];
    __shared__ float red[K_CODE];
    int tid = threadIdx.x;

#pragma unroll
    for (int i = 0; i < 4; ++i) {
        int k = tid + 256 * i;
        float oh = 0.f;
        for (int r = 0; r < nrep; ++r) oh += onehot_rep[(size_t)r * K_CODE + k];
        float ncs = DECAYF * cluster_size[k] + (1.0f - DECAYF) * oh;
        ncs_s[k] = ncs;
        red[k] = ncs;
    }
    __syncthreads();
    for (int s = 512; s > 0; s >>= 1) {
        for (int idx = tid; idx < s; idx += 256) red[idx] += red[idx + s];
        __syncthreads();
    }
    float n = red[0];

    if (blockIdx.x == 0) {
#pragma unroll
        for (int i = 0; i < 4; ++i) {
            int k = tid + 256 * i;
            out_ncs[k] = ncs_s[k];
        }
        if (tid == 0) out_diff[0] = ws_diff[0] * (1.0f / 4194304.0f);  // /2^22 exact
    }

    int k = blockIdx.x * 16 + (tid >> 4);  // row (same mapping as before)
    int c = tid & 15;                      // float4 chunk
    float ncs = ncs_s[k];
    float cs = (ncs + EPSF) / (n + (float)K_CODE * EPSF) * n;

    size_t off = (size_t)k * E_DIM + (size_t)c * 4;
    float4 s4 = make_float4(0.f, 0.f, 0.f, 0.f);
    for (int r = 0; r < nrep; ++r) {
        float4 v = *reinterpret_cast<const float4*>(esum_rep + (size_t)r * (K_CODE * E_DIM) + off);
        s4.x += v.x; s4.y += v.y; s4.z += v.z; s4.w += v.w;
    }
    float4 a = *reinterpret_cast<const float4*>(embed_avg + off);
    float4 nea, ne;
    nea.x = DECAYF * a.x + (1.0f - DECAYF) * s4.x;
    nea.y = DECAYF * a.y + (1.0f - DECAYF) * s4.y;
    nea.z = DECAYF * a.z + (1.0f - DECAYF) * s4.z;
    nea.w = DECAYF * a.w + (1.0f - DECAYF) * s4.w;
    ne.x = nea.x / cs; ne.y = nea.y / cs; ne.z = nea.z / cs; ne.w = nea.w / cs;
    *reinterpret_cast<float4*>(out_nea + off) = nea;
    *reinterpret_cast<float4*>(out_ne + off) = ne;
}

extern "C" void kernel_launch(void* const* d_in, const int* in_sizes, int n_in,
                              void* d_out, int out_size, void* d_ws, size_t ws_size,
                              hipStream_t stream) {
    const float* z_e = (const float*)d_in[0];
    const float* embed = (const float*)d_in[1];
    const float* cluster_size = (const float*)d_in[2];
    const float* embed_avg = (const float*)d_in[3];

    float* out = (float*)d_out;
    float* o_zq = out;                   // 4194304
    float* o_diff = out + 4194304;       // 1
    float* o_ind = out + 4194305;        // 65536
    float* o_ne = out + 4194305 + 65536; // 65536
    float* o_ncs = o_ne + 65536;         // 1024
    float* o_nea = o_ncs + 1024;         // 65536

    float* ws = (float*)d_ws;
    float* ws_diff = ws + 0;
    float* ws_onehot = ws + 16;          // 8*1024

    int nrep = 1;
    while (nrep < 8 &&
           (size_t)(8208 + (size_t)(2 * nrep) * 65536 + 262144) * sizeof(float) <= ws_size)
        nrep *= 2;

    float* ws_esum = ws + 8208;                                   // nrep*65536
    unsigned long long* ws_keys2 =
        (unsigned long long*)(ws + 8208 + (size_t)nrep * 65536);  // u64[65536][2]

    // one contiguous clear: diff, pad, onehot, esum (keys2 fully overwritten)
    hipMemsetAsync(ws, 0, (size_t)(8208 + (size_t)nrep * 65536) * sizeof(float), stream);

    dist_kernel<<<(T_TOK / TT) * 2, 512, 0, stream>>>(z_e, embed, ws_keys2);
    combine_kernel<<<T_TOK / 64, 256, 0, stream>>>(z_e, embed, ws_keys2, o_zq, o_ind,
                                                   ws_diff, ws_esum, ws_onehot, nrep - 1);
    finalize_kernel<<<64, 256, 0, stream>>>(cluster_size, ws_onehot, ws_diff, embed_avg,
                                            ws_esum, o_diff, o_ncs, o_ne, o_nea, nrep);
}